// Round 12
// baseline (246.927 us; speedup 1.0000x reference)
//
#include <hip/hip_runtime.h>
#include <math.h>

// Problem constants
#define N_TOK 32768
#define KCB   4096
#define SPLITS 8
#define CPSW  512    // codes per split
#define TILES 32     // CPSW/16

// Output layout (flat float32)
#define OFF_ZQST   0
#define OFF_ZQ     2097152
#define OFF_IDX    4194304
#define OFF_STATS  4227072
#define OFF_NEWEMB 4227074
#define OFF_NEWCS  4489218
#define OFF_NEWEMA 4493314

// Workspace layout (bytes)
#define WS_FN       0          // 8388608
#define WS_ESUM     8388608    // 1048576 (zeroed by k_prep)
#define WS_USAGE    9437184    // 16384   (zeroed by k_prep)
#define WS_CNTS     9453568    // 1024    (zeroed by k_prep; cnts[0]=flagcnt, scal[] at +16)
#define WS_FULLKEY  9454592    // 262144  (init by k_merge)
#define WS_EHI      9716736    // 524288
#define WS_ELO      10241024   // 524288
#define WS_PK1      10765312   // 1048576 (8 splits)
#define WS_PK2      11813888   // 1048576
#define WS_IDXW     12862464   // 131072
#define WS_RIDX     12993536   // 16384
#define WS_FULL     13009920   // 131072

// 131072 keys = 128 x-ulps = 1.22e-4 dot gap; covers split-bf16 error (~1e-5) ~10x
#define THRKEY 131072u

typedef __attribute__((ext_vector_type(8))) short short8;
typedef __attribute__((ext_vector_type(4))) float float4v;

__device__ __forceinline__ float wave_sum(float v) {
#pragma unroll
  for (int off = 32; off > 0; off >>= 1) v += __shfl_xor(v, off, 64);
  return v;
}

// round-to-nearest-even f32 -> bf16 bits
__device__ __forceinline__ unsigned short f2bf(float f) {
  unsigned u = __float_as_uint(f);
  unsigned r = (u + 0x7fffu + ((u >> 16) & 1u)) >> 16;
  return (unsigned short)r;
}
__device__ __forceinline__ float bf2f(unsigned short h) {
  return __uint_as_float(((unsigned)h) << 16);
}

// ---------------- Threefry-2x32 (20 rounds), bit-exact vs JAX ----------------
__device__ __forceinline__ unsigned rotl32(unsigned x, int d) {
  return (x << d) | (x >> (32 - d));
}
__device__ __forceinline__ void tf2x32(unsigned k0, unsigned k1,
                                       unsigned x0, unsigned x1,
                                       unsigned& o0, unsigned& o1) {
  unsigned ks2 = k0 ^ k1 ^ 0x1BD11BDAu;
  unsigned v0 = x0 + k0, v1 = x1 + k1;
  v0 += v1; v1 = rotl32(v1, 13) ^ v0;
  v0 += v1; v1 = rotl32(v1, 15) ^ v0;
  v0 += v1; v1 = rotl32(v1, 26) ^ v0;
  v0 += v1; v1 = rotl32(v1, 6) ^ v0;
  v0 += k1; v1 += ks2 + 1u;
  v0 += v1; v1 = rotl32(v1, 17) ^ v0;
  v0 += v1; v1 = rotl32(v1, 29) ^ v0;
  v0 += v1; v1 = rotl32(v1, 16) ^ v0;
  v0 += v1; v1 = rotl32(v1, 24) ^ v0;
  v0 += ks2; v1 += k0 + 2u;
  v0 += v1; v1 = rotl32(v1, 13) ^ v0;
  v0 += v1; v1 = rotl32(v1, 15) ^ v0;
  v0 += v1; v1 = rotl32(v1, 26) ^ v0;
  v0 += v1; v1 = rotl32(v1, 6) ^ v0;
  v0 += k0; v1 += k1 + 3u;
  v0 += v1; v1 = rotl32(v1, 17) ^ v0;
  v0 += v1; v1 = rotl32(v1, 29) ^ v0;
  v0 += v1; v1 = rotl32(v1, 16) ^ v0;
  v0 += v1; v1 = rotl32(v1, 24) ^ v0;
  v0 += k1; v1 += ks2 + 4u;
  v0 += v1; v1 = rotl32(v1, 13) ^ v0;
  v0 += v1; v1 = rotl32(v1, 15) ^ v0;
  v0 += v1; v1 = rotl32(v1, 26) ^ v0;
  v0 += v1; v1 = rotl32(v1, 6) ^ v0;
  v0 += ks2; v1 += k0 + 5u;
  o0 = v0; o1 = v1;
}

// ---- fused prep: norm | emb hi/lo | ridx | zero(esum,usage,cnts+scal) ----
__global__ __launch_bounds__(256) void k_prep(const float* __restrict__ z_e,
                                              const float* __restrict__ emb,
                                              float* __restrict__ fn,
                                              unsigned short* __restrict__ ehi,
                                              unsigned short* __restrict__ elo,
                                              int* __restrict__ ridx,
                                              int* __restrict__ zbase) {
  int b = blockIdx.x;
  int t = threadIdx.x;
  if (b < 8192) {
    int n = b * 4 + (t >> 6);
    int lane = t & 63;
    float x = z_e[n * 64 + lane];
    float ss = wave_sum(x * x);
    fn[n * 64 + lane] = x / fmaxf(sqrtf(ss), 1e-8f);
  } else if (b < 9216) {
    int i = (b - 8192) * 256 + t;
    float x = emb[i];
    unsigned short h = f2bf(x);
    ehi[i] = h;
    elo[i] = f2bf(x - bf2f(h));
  } else if (b < 9224) {
    int j = (b - 9216) * 256 + t;  // 0..2047
    unsigned a0, b0, a1, b1;
    tf2x32(0u, 1u, 0u, 2u, a0, b0);
    tf2x32(0u, 1u, 1u, 3u, a1, b1);
    unsigned o0, o1;
    tf2x32(b0, b1, (unsigned)j, (unsigned)(j + 2048), o0, o1);
    ridx[j] = (int)(o0 & 32767u);
    ridx[j + 2048] = (int)(o1 & 32767u);
  } else {
    // zero esum (262144) + usage (4096) + cnts/scal (256) = 266496 ints = 1041 blocks
    int i = (b - 9224) * 256 + t;
    zbase[i] = 0;
  }
}

// ---------------- MFMA dots + per-split packed top-2 ----------------
// 32 queries/wave (2 subtiles) -> ~116 regs, fits the 128 budget of
// launch_bounds(256,4): 4 blocks/CU. grid (256,8) = 2048 = two full
// tail-free rounds of 8 blocks/CU.
// Loads batched 3 tiles ahead (3 named buffer sets, 12 loads in flight/wave):
// per-tile load-stall (the measured ~4400cyc/tile constant across R5/R8/R11)
// amortized over 3 tiles of MFMA work and 4 waves/SIMD.
// A frags pre-scaled by 0.125; acc C-init 1.125 -> acc = 0.125*dot+1.125 in
// [1,1.25) single binade -> key = (bits<<10)+(511-idx) exactly monotone.
__global__ __launch_bounds__(256, 4) void k_dots(const float* __restrict__ fn,
                                                 const unsigned short* __restrict__ ehi,
                                                 const unsigned short* __restrict__ elo,
                                                 unsigned* __restrict__ pk1,
                                                 unsigned* __restrict__ pk2) {
  int t = threadIdx.x;
  int wave = t >> 6, lane = t & 63;
  int g = lane >> 4, n = lane & 15;
  int qw = blockIdx.x * 128 + wave * 32;  // wave's 32 queries
  int split = blockIdx.y;                 // 0..7

  // A fragments (hi+lo in regs, pre-scaled by 0.125)
  short8 ahi[2][2], alo[2][2];
#pragma unroll
  for (int s = 0; s < 2; s++)
#pragma unroll
    for (int ks = 0; ks < 2; ks++) {
      const float* src = fn + (qw + s * 16 + n) * 64 + ks * 32 + g * 8;
      short8 h, l;
#pragma unroll
      for (int j = 0; j < 8; j++) {
        float f = src[j] * 0.125f;  // exact pow2 scale
        unsigned short hu = f2bf(f);
        h[j] = (short)hu;
        l[j] = (short)f2bf(f - bf2f(hu));
      }
      ahi[s][ks] = h;
      alo[s][ks] = l;
    }

  unsigned run1[2][4], run2[2][4];
#pragma unroll
  for (int s = 0; s < 2; s++)
#pragma unroll
    for (int r = 0; r < 4; r++) { run1[s][r] = 0u; run2[s][r] = 0u; }

  const unsigned short* bh = ehi + (split * CPSW + n) * 64 + g * 8;
  const unsigned short* bl = elo + (split * CPSW + n) * 64 + g * 8;
  const float hiclamp = __uint_as_float(0x3F9FFFFFu);  // 1.25 - 1ulp

  // 3 named buffer sets (NO arrays -> no scratch spill)
  short8 Ah0 = *(const short8*)(bh);
  short8 Ah1 = *(const short8*)(bh + 32);
  short8 Al0 = *(const short8*)(bl);
  short8 Al1 = *(const short8*)(bl + 32);
  short8 Bh0 = *(const short8*)(bh + 1024);
  short8 Bh1 = *(const short8*)(bh + 1024 + 32);
  short8 Bl0 = *(const short8*)(bl + 1024);
  short8 Bl1 = *(const short8*)(bl + 1024 + 32);
  short8 Ch0 = *(const short8*)(bh + 2048);
  short8 Ch1 = *(const short8*)(bh + 2048 + 32);
  short8 Cl0 = *(const short8*)(bl + 2048);
  short8 Cl1 = *(const short8*)(bl + 2048 + 32);

// 12 MFMAs (2 subtiles x 6 products) + top-2 select for one 16-code tile
#define TILE(H0, H1, L0, L1, KT)                                                \
  {                                                                             \
    float4v a0 = (float4v){1.125f, 1.125f, 1.125f, 1.125f};                     \
    float4v a1 = a0;                                                            \
    a0 = __builtin_amdgcn_mfma_f32_16x16x32_bf16(alo[0][0], H0, a0, 0, 0, 0);   \
    a1 = __builtin_amdgcn_mfma_f32_16x16x32_bf16(alo[1][0], H0, a1, 0, 0, 0);   \
    a0 = __builtin_amdgcn_mfma_f32_16x16x32_bf16(alo[0][1], H1, a0, 0, 0, 0);   \
    a1 = __builtin_amdgcn_mfma_f32_16x16x32_bf16(alo[1][1], H1, a1, 0, 0, 0);   \
    a0 = __builtin_amdgcn_mfma_f32_16x16x32_bf16(ahi[0][0], L0, a0, 0, 0, 0);   \
    a1 = __builtin_amdgcn_mfma_f32_16x16x32_bf16(ahi[1][0], L0, a1, 0, 0, 0);   \
    a0 = __builtin_amdgcn_mfma_f32_16x16x32_bf16(ahi[0][1], L1, a0, 0, 0, 0);   \
    a1 = __builtin_amdgcn_mfma_f32_16x16x32_bf16(ahi[1][1], L1, a1, 0, 0, 0);   \
    a0 = __builtin_amdgcn_mfma_f32_16x16x32_bf16(ahi[0][0], H0, a0, 0, 0, 0);   \
    a1 = __builtin_amdgcn_mfma_f32_16x16x32_bf16(ahi[1][0], H0, a1, 0, 0, 0);   \
    a0 = __builtin_amdgcn_mfma_f32_16x16x32_bf16(ahi[0][1], H1, a0, 0, 0, 0);   \
    a1 = __builtin_amdgcn_mfma_f32_16x16x32_bf16(ahi[1][1], H1, a1, 0, 0, 0);   \
    unsigned invb = 511u - (unsigned)((KT) * 16) - (unsigned)n;                 \
    _Pragma("unroll") for (int r = 0; r < 4; r++) {                             \
      float x0 = __builtin_amdgcn_fmed3f(a0[r], 1.0f, hiclamp);                 \
      unsigned kb0 = (__float_as_uint(x0) << 10) + invb;                        \
      run2[0][r] = max(run2[0][r], min(run1[0][r], kb0));                       \
      run1[0][r] = max(run1[0][r], kb0);                                        \
      float x1 = __builtin_amdgcn_fmed3f(a1[r], 1.0f, hiclamp);                 \
      unsigned kb1 = (__float_as_uint(x1) << 10) + invb;                        \
      run2[1][r] = max(run2[1][r], min(run1[1][r], kb1));                       \
      run1[1][r] = max(run1[1][r], kb1);                                        \
    }                                                                           \
  }

#define REFILL(H0, H1, L0, L1, KT)                                              \
  {                                                                             \
    int off = (KT) * 1024;  /* overreads past split end are in-bounds ws */     \
    H0 = *(const short8*)(bh + off);                                            \
    H1 = *(const short8*)(bh + off + 32);                                       \
    L0 = *(const short8*)(bl + off);                                            \
    L1 = *(const short8*)(bl + off + 32);                                       \
  }

#pragma unroll 1
  for (int kt = 0; kt < 30; kt += 3) {
    TILE(Ah0, Ah1, Al0, Al1, kt)
    REFILL(Ah0, Ah1, Al0, Al1, kt + 3)
    TILE(Bh0, Bh1, Bl0, Bl1, kt + 1)
    REFILL(Bh0, Bh1, Bl0, Bl1, kt + 4)
    TILE(Ch0, Ch1, Cl0, Cl1, kt + 2)
    REFILL(Ch0, Ch1, Cl0, Cl1, kt + 5)
  }
  // tail: tiles 30, 31 (already loaded in A, B)
  TILE(Ah0, Ah1, Al0, Al1, 30)
  TILE(Bh0, Bh1, Bl0, Bl1, 31)
#undef TILE
#undef REFILL

  // butterfly top-2 merge across the 16 n-lanes (same query per g,s,r)
#pragma unroll
  for (int off = 1; off <= 8; off <<= 1) {
#pragma unroll
    for (int s = 0; s < 2; s++)
#pragma unroll
      for (int r = 0; r < 4; r++) {
        unsigned o1 = (unsigned)__shfl_xor((int)run1[s][r], off, 64);
        unsigned o2 = (unsigned)__shfl_xor((int)run2[s][r], off, 64);
        run2[s][r] = max(min(run1[s][r], o1), max(run2[s][r], o2));
        run1[s][r] = max(run1[s][r], o1);
      }
  }

  if (n == 0) {
#pragma unroll
    for (int s = 0; s < 2; s++)
#pragma unroll
      for (int r = 0; r < 4; r++) {
        int q = qw + s * 16 + g * 4 + r;
        pk1[split * N_TOK + q] = run1[s][r];
        pk2[split * N_TOK + q] = run2[s][r];
      }
  }
}

// ---------------- merge splits, flag near-ties, init fullkey ----------------
__global__ __launch_bounds__(256) void k_merge(const unsigned* __restrict__ pk1,
                                               const unsigned* __restrict__ pk2,
                                               int* __restrict__ idxw,
                                               int* __restrict__ cnts,
                                               int* __restrict__ full,
                                               unsigned long long* __restrict__ fullkey) {
  int q = blockIdx.x * 256 + threadIdx.x;
  unsigned b1 = 0u, b2 = 0u;
  int s1 = 0;
#pragma unroll
  for (int s = 0; s < SPLITS; s++) {
    unsigned k1 = pk1[s * N_TOK + q];
    unsigned k2 = pk2[s * N_TOK + q];
    b2 = max(b2, min(b1, k1));
    b2 = max(b2, k2);
    if (k1 > b1) { b1 = k1; s1 = s; }
  }
  idxw[q] = s1 * CPSW + 511 - (int)(b1 & 1023u);
  fullkey[q] = 0ull;
  if (b1 - b2 < THRKEY) {
    int p = atomicAdd(&cnts[0], 1);
    full[p] = q;
  }
}

// ---------------- exact fp64 full rescan, parallel over (query, chunk) ------
__global__ __launch_bounds__(256) void k_fix_full(const int* __restrict__ cnts,
                                                  const int* __restrict__ full,
                                                  const float* __restrict__ fn,
                                                  const float* __restrict__ emb,
                                                  unsigned long long* __restrict__ fullkey) {
  __shared__ float sfn[64];
  __shared__ unsigned long long red[256];
  int t = threadIdx.x;
  int total = cnts[0] * 16;
  for (int w = blockIdx.x; w < total; w += gridDim.x) {
    int q = full[w >> 4];
    int c = (w & 15) * 256 + t;
    __syncthreads();
    if (t < 64) sfn[t] = fn[q * 64 + t];
    __syncthreads();
    const float* er = emb + c * 64;
    double s0 = 0, s1 = 0, s2 = 0, s3 = 0;
    for (int k = 0; k < 16; k++) {
      s0 += (double)er[k] * (double)sfn[k];
      s1 += (double)er[k + 16] * (double)sfn[k + 16];
      s2 += (double)er[k + 32] * (double)sfn[k + 32];
      s3 += (double)er[k + 48] * (double)sfn[k + 48];
    }
    double d = (s0 + s1) + (s2 + s3);
    unsigned long long key =
        ((unsigned long long)__double_as_longlong(d + 2.0) & ~0xFFFULL) |
        (unsigned long long)(4095 - c);
    red[t] = key;
    __syncthreads();
    for (int s = 128; s > 0; s >>= 1) {
      if (t < s) red[t] = red[t] > red[t + s] ? red[t] : red[t + s];
      __syncthreads();
    }
    if (t == 0) atomicMax(&fullkey[q], red[0]);
  }
}

// ---------------- write z_q, z_q_st, indices + scatter stats ----------------
__global__ __launch_bounds__(256) void k_write_scatter(const int* __restrict__ idxw,
                                                       const unsigned long long* __restrict__ fullkey,
                                                       const float* __restrict__ z_e,
                                                       const float* __restrict__ emb,
                                                       const float* __restrict__ fn,
                                                       float* __restrict__ out,
                                                       float* __restrict__ esum,
                                                       float* __restrict__ usage) {
  int t = threadIdx.x;
  int nn = blockIdx.x * 4 + (t >> 6);
  int lane = t & 63;
  unsigned long long fk = fullkey[nn];
  int bi = fk ? (4095 - (int)(fk & 0xFFFULL)) : idxw[nn];
  float v = emb[bi * 64 + lane];
  float ze = z_e[nn * 64 + lane];
  out[OFF_ZQST + nn * 64 + lane] = ze + (v - ze);
  out[OFF_ZQ + nn * 64 + lane] = v;
  atomicAdd(&esum[bi * 64 + lane], fn[nn * 64 + lane]);
  if (lane == 0) {
    out[OFF_IDX + nn] = (float)bi;
    atomicAdd(&usage[bi], 1.0f);
  }
}

// ---- stats partials (16 blocks): usage.sum()==32768 exactly, so entropy
// needs no prior global reduction. scal[0]=entropy, [1]=dead, [2]=cs-sum.
__global__ __launch_bounds__(256) void k_stats(const float* __restrict__ usage,
                                               const float* __restrict__ ema_cs,
                                               float* __restrict__ scal) {
  __shared__ float rE[4], rD[4], rC[4];
  int t = threadIdx.x;
  int i = blockIdx.x * 256 + t;  // 0..4095
  float u = usage[i];
  float p = u * (1.0f / 32768.0f);
  float ent = (p > 0.f) ? p * logf(p) : 0.f;
  float dead = (u == 0.f) ? 1.f : 0.f;
  float cs = 0.99f * ema_cs[i] + 0.01f * u;
  ent = wave_sum(ent);
  dead = wave_sum(dead);
  cs = wave_sum(cs);
  int w = t >> 6, lane = t & 63;
  if (lane == 0) { rE[w] = ent; rD[w] = dead; rC[w] = cs; }
  __syncthreads();
  if (t == 0) {
    atomicAdd(&scal[0], rE[0] + rE[1] + rE[2] + rE[3]);
    atomicAdd(&scal[1], rD[0] + rD[1] + rD[2] + rD[3]);
    atomicAdd(&scal[2], rC[0] + rC[1] + rC[2] + rC[3]);
  }
}

// ---------------- new_cs, new_ema_emb, new_embedding, stats assembly --------
__global__ __launch_bounds__(256) void k_final(const float* __restrict__ usage,
                                               const float* __restrict__ ema_cs,
                                               const float* __restrict__ ema_emb,
                                               const float* __restrict__ esum,
                                               const float* __restrict__ fn,
                                               const int* __restrict__ ridx,
                                               const float* __restrict__ scal,
                                               float* __restrict__ out) {
  int t = threadIdx.x;
  int k = blockIdx.x * 4 + (t >> 6);
  int lane = t & 63;
  if (blockIdx.x == 0 && t == 0) {
    out[OFF_STATS + 0] = expf(-scal[0]);
    out[OFF_STATS + 1] = scal[1] * (1.0f / 4096.0f);
  }
  float u = usage[k];
  float ncs = 0.99f * ema_cs[k] + 0.01f * u;
  if (lane == 0) out[OFF_NEWCS + k] = ncs;
  float nee = 0.99f * ema_emb[k * 64 + lane] + 0.01f * esum[k * 64 + lane];
  out[OFF_NEWEMA + k * 64 + lane] = nee;

  float n = scal[2];
  float smoothed = (ncs + 1e-5f) / (n + 4096.0f * 1e-5f);
  float ne = nee / fmaxf(smoothed, 1e-5f);
  float ss = wave_sum(ne * ne);
  ne = ne / fmaxf(sqrtf(ss), 1e-8f);

  float res;
  if (u <= 0.f) {
    int rsrc = ridx[k];
    float v = fn[rsrc * 64 + lane];
    float s2 = wave_sum(v * v);
    res = v / fmaxf(sqrtf(s2), 1e-8f);
  } else {
    res = ne;
  }
  out[OFF_NEWEMB + k * 64 + lane] = res;
}

extern "C" void kernel_launch(void* const* d_in, const int* in_sizes, int n_in,
                              void* d_out, int out_size, void* d_ws, size_t ws_size,
                              hipStream_t stream) {
  const float* z_e = (const float*)d_in[0];
  const float* emb = (const float*)d_in[1];
  const float* ema_cs = (const float*)d_in[2];
  const float* ema_emb = (const float*)d_in[3];
  float* out = (float*)d_out;
  char* ws = (char*)d_ws;

  float* fn = (float*)(ws + WS_FN);
  float* esum = (float*)(ws + WS_ESUM);
  float* usage = (float*)(ws + WS_USAGE);
  int* cnts = (int*)(ws + WS_CNTS);
  float* scal = (float*)(ws + WS_CNTS + 16);
  unsigned long long* fullkey = (unsigned long long*)(ws + WS_FULLKEY);
  unsigned short* ehi = (unsigned short*)(ws + WS_EHI);
  unsigned short* elo = (unsigned short*)(ws + WS_ELO);
  unsigned* pk1 = (unsigned*)(ws + WS_PK1);
  unsigned* pk2 = (unsigned*)(ws + WS_PK2);
  int* idxw = (int*)(ws + WS_IDXW);
  int* ridx = (int*)(ws + WS_RIDX);
  int* full = (int*)(ws + WS_FULL);

  k_prep<<<10265, 256, 0, stream>>>(z_e, emb, fn, ehi, elo, ridx, (int*)(ws + WS_ESUM));
  k_dots<<<dim3(256, SPLITS), 256, 0, stream>>>(fn, ehi, elo, pk1, pk2);
  k_merge<<<128, 256, 0, stream>>>(pk1, pk2, idxw, cnts, full, fullkey);
  k_fix_full<<<2048, 256, 0, stream>>>(cnts, full, fn, emb, fullkey);
  k_write_scatter<<<8192, 256, 0, stream>>>(idxw, fullkey, z_e, emb, fn, out, esum, usage);
  k_stats<<<16, 256, 0, stream>>>(usage, ema_cs, scal);
  k_final<<<1024, 256, 0, stream>>>(usage, ema_cs, ema_emb, esum, fn, ridx, scal, out);
}

// Round 13
// 173.535 us; speedup vs baseline: 1.4229x; 1.4229x over previous
//
#include <hip/hip_runtime.h>
#include <math.h>

// Problem constants
#define N_TOK 32768
#define KCB   4096
#define SPLITS 6
// per-split tile counts (even): {44,44,42,42,42,42}, sum = 256 tiles = 4096 codes

// Output layout (flat float32)
#define OFF_ZQST   0
#define OFF_ZQ     2097152
#define OFF_IDX    4194304
#define OFF_STATS  4227072
#define OFF_NEWEMB 4227074
#define OFF_NEWCS  4489218
#define OFF_NEWEMA 4493314

// Workspace layout (bytes)
#define WS_FN       0          // 8388608
#define WS_ESUM     8388608    // 1048576 (zeroed by k_prep)
#define WS_USAGE    9437184    // 16384   (zeroed by k_prep)
#define WS_CNTS     9453568    // 1024    (zeroed by k_prep; cnts[0]=fullcnt, scal[] at +16)
#define WS_FULLKEY  9454592    // 262144  (init by k_merge_fix)
#define WS_EHI      9716736    // 524288
#define WS_ELO      10241024   // 524288
#define WS_PK1      10765312   // 786432 (6 splits)
#define WS_PK2      11551744   // 786432
#define WS_IDXW     12338176   // 131072
#define WS_RIDX     12469248   // 16384
#define WS_FULL     12485632   // 131072

// 131072 keys = 128 x-ulps = 1.22e-4 dot gap
#define THRKEY 131072u
// danger margin for hidden-3rd-in-split: 98304 keys = 9.2e-5 dot
#define DGRKEY 98304u

typedef __attribute__((ext_vector_type(8))) short short8;
typedef __attribute__((ext_vector_type(4))) float float4v;

__device__ __forceinline__ float wave_sum(float v) {
#pragma unroll
  for (int off = 32; off > 0; off >>= 1) v += __shfl_xor(v, off, 64);
  return v;
}

// round-to-nearest-even f32 -> bf16 bits
__device__ __forceinline__ unsigned short f2bf(float f) {
  unsigned u = __float_as_uint(f);
  unsigned r = (u + 0x7fffu + ((u >> 16) & 1u)) >> 16;
  return (unsigned short)r;
}
__device__ __forceinline__ float bf2f(unsigned short h) {
  return __uint_as_float(((unsigned)h) << 16);
}

// ---------------- Threefry-2x32 (20 rounds), bit-exact vs JAX ----------------
__device__ __forceinline__ unsigned rotl32(unsigned x, int d) {
  return (x << d) | (x >> (32 - d));
}
__device__ __forceinline__ void tf2x32(unsigned k0, unsigned k1,
                                       unsigned x0, unsigned x1,
                                       unsigned& o0, unsigned& o1) {
  unsigned ks2 = k0 ^ k1 ^ 0x1BD11BDAu;
  unsigned v0 = x0 + k0, v1 = x1 + k1;
  v0 += v1; v1 = rotl32(v1, 13) ^ v0;
  v0 += v1; v1 = rotl32(v1, 15) ^ v0;
  v0 += v1; v1 = rotl32(v1, 26) ^ v0;
  v0 += v1; v1 = rotl32(v1, 6) ^ v0;
  v0 += k1; v1 += ks2 + 1u;
  v0 += v1; v1 = rotl32(v1, 17) ^ v0;
  v0 += v1; v1 = rotl32(v1, 29) ^ v0;
  v0 += v1; v1 = rotl32(v1, 16) ^ v0;
  v0 += v1; v1 = rotl32(v1, 24) ^ v0;
  v0 += ks2; v1 += k0 + 2u;
  v0 += v1; v1 = rotl32(v1, 13) ^ v0;
  v0 += v1; v1 = rotl32(v1, 15) ^ v0;
  v0 += v1; v1 = rotl32(v1, 26) ^ v0;
  v0 += v1; v1 = rotl32(v1, 6) ^ v0;
  v0 += k0; v1 += k1 + 3u;
  v0 += v1; v1 = rotl32(v1, 17) ^ v0;
  v0 += v1; v1 = rotl32(v1, 29) ^ v0;
  v0 += v1; v1 = rotl32(v1, 16) ^ v0;
  v0 += v1; v1 = rotl32(v1, 24) ^ v0;
  v0 += k1; v1 += ks2 + 4u;
  v0 += v1; v1 = rotl32(v1, 13) ^ v0;
  v0 += v1; v1 = rotl32(v1, 15) ^ v0;
  v0 += v1; v1 = rotl32(v1, 26) ^ v0;
  v0 += v1; v1 = rotl32(v1, 6) ^ v0;
  v0 += ks2; v1 += k0 + 5u;
  o0 = v0; o1 = v1;
}

// ---- fused prep: norm | emb hi/lo | ridx | zero(esum,usage,cnts+scal) ----
__global__ __launch_bounds__(256) void k_prep(const float* __restrict__ z_e,
                                              const float* __restrict__ emb,
                                              float* __restrict__ fn,
                                              unsigned short* __restrict__ ehi,
                                              unsigned short* __restrict__ elo,
                                              int* __restrict__ ridx,
                                              int* __restrict__ zbase) {
  int b = blockIdx.x;
  int t = threadIdx.x;
  if (b < 8192) {
    int n = b * 4 + (t >> 6);
    int lane = t & 63;
    float x = z_e[n * 64 + lane];
    float ss = wave_sum(x * x);
    fn[n * 64 + lane] = x / fmaxf(sqrtf(ss), 1e-8f);
  } else if (b < 9216) {
    int i = (b - 8192) * 256 + t;
    float x = emb[i];
    unsigned short h = f2bf(x);
    ehi[i] = h;
    elo[i] = f2bf(x - bf2f(h));
  } else if (b < 9224) {
    int j = (b - 9216) * 256 + t;  // 0..2047
    unsigned a0, b0, a1, b1;
    tf2x32(0u, 1u, 0u, 2u, a0, b0);
    tf2x32(0u, 1u, 1u, 3u, a1, b1);
    unsigned o0, o1;
    tf2x32(b0, b1, (unsigned)j, (unsigned)(j + 2048), o0, o1);
    ridx[j] = (int)(o0 & 32767u);
    ridx[j + 2048] = (int)(o1 & 32767u);
  } else {
    // zero esum (262144) + usage (4096) + cnts/scal (256) = 266496 ints = 1041 blocks
    int i = (b - 9224) * 256 + t;
    zbase[i] = 0;
  }
}

// ---------------- MFMA dots + per-split packed top-2 (R11 kernel) ----------
__global__ __launch_bounds__(256, 3) void k_dots(const float* __restrict__ fn,
                                                 const unsigned short* __restrict__ ehi,
                                                 const unsigned short* __restrict__ elo,
                                                 unsigned* __restrict__ pk1,
                                                 unsigned* __restrict__ pk2) {
  int t = threadIdx.x;
  int wave = t >> 6, lane = t & 63;
  int g = lane >> 4, n = lane & 15;
  int qw = blockIdx.x * 256 + wave * 64;  // wave's 64 queries
  int split = blockIdx.y;                 // 0..5
  int nt16 = (split < 2) ? 704 : 672;     // codes in this split
  int tstart16 = (split < 3) ? 704 * split : 672 * split + 64;
  int ntiles = nt16 >> 4;                 // 44 or 42 (even)

  // A fragments (hi+lo in regs, pre-scaled by 0.125)
  short8 ahi[4][2], alo[4][2];
#pragma unroll
  for (int s = 0; s < 4; s++)
#pragma unroll
    for (int ks = 0; ks < 2; ks++) {
      const float* src = fn + (qw + s * 16 + n) * 64 + ks * 32 + g * 8;
      short8 h, l;
#pragma unroll
      for (int j = 0; j < 8; j++) {
        float f = src[j] * 0.125f;  // exact pow2 scale
        unsigned short hu = f2bf(f);
        h[j] = (short)hu;
        l[j] = (short)f2bf(f - bf2f(hu));
      }
      ahi[s][ks] = h;
      alo[s][ks] = l;
    }

  unsigned run1[4][4], run2[4][4];
#pragma unroll
  for (int s = 0; s < 4; s++)
#pragma unroll
    for (int r = 0; r < 4; r++) { run1[s][r] = 0u; run2[s][r] = 0u; }

  const unsigned short* bh = ehi + (tstart16 + n) * 64 + g * 8;
  const unsigned short* bl = elo + (tstart16 + n) * 64 + g * 8;
  const float hiclamp = __uint_as_float(0x3F9FFFFFu);  // 1.25 - 1ulp

  // named double-buffer (NO arrays -> no scratch spill)
  short8 h0a = *(const short8*)(bh);
  short8 h1a = *(const short8*)(bh + 32);
  short8 l0a = *(const short8*)(bl);
  short8 l1a = *(const short8*)(bl + 32);
  short8 h0b = *(const short8*)(bh + 1024);
  short8 h1b = *(const short8*)(bh + 1024 + 32);
  short8 l0b = *(const short8*)(bl + 1024);
  short8 l1b = *(const short8*)(bl + 1024 + 32);

#define MFMA_BLOCK(H0, H1, L0, L1)                                              \
    float4v a0 = (float4v){1.125f, 1.125f, 1.125f, 1.125f};                     \
    float4v a1 = a0, a2 = a0, a3 = a0;                                          \
    a0 = __builtin_amdgcn_mfma_f32_16x16x32_bf16(alo[0][0], H0, a0, 0, 0, 0);   \
    a1 = __builtin_amdgcn_mfma_f32_16x16x32_bf16(alo[1][0], H0, a1, 0, 0, 0);   \
    a2 = __builtin_amdgcn_mfma_f32_16x16x32_bf16(alo[2][0], H0, a2, 0, 0, 0);   \
    a3 = __builtin_amdgcn_mfma_f32_16x16x32_bf16(alo[3][0], H0, a3, 0, 0, 0);   \
    a0 = __builtin_amdgcn_mfma_f32_16x16x32_bf16(alo[0][1], H1, a0, 0, 0, 0);   \
    a1 = __builtin_amdgcn_mfma_f32_16x16x32_bf16(alo[1][1], H1, a1, 0, 0, 0);   \
    a2 = __builtin_amdgcn_mfma_f32_16x16x32_bf16(alo[2][1], H1, a2, 0, 0, 0);   \
    a3 = __builtin_amdgcn_mfma_f32_16x16x32_bf16(alo[3][1], H1, a3, 0, 0, 0);   \
    a0 = __builtin_amdgcn_mfma_f32_16x16x32_bf16(ahi[0][0], L0, a0, 0, 0, 0);   \
    a1 = __builtin_amdgcn_mfma_f32_16x16x32_bf16(ahi[1][0], L0, a1, 0, 0, 0);   \
    a2 = __builtin_amdgcn_mfma_f32_16x16x32_bf16(ahi[2][0], L0, a2, 0, 0, 0);   \
    a3 = __builtin_amdgcn_mfma_f32_16x16x32_bf16(ahi[3][0], L0, a3, 0, 0, 0);   \
    a0 = __builtin_amdgcn_mfma_f32_16x16x32_bf16(ahi[0][1], L1, a0, 0, 0, 0);   \
    a1 = __builtin_amdgcn_mfma_f32_16x16x32_bf16(ahi[1][1], L1, a1, 0, 0, 0);   \
    a2 = __builtin_amdgcn_mfma_f32_16x16x32_bf16(ahi[2][1], L1, a2, 0, 0, 0);   \
    a3 = __builtin_amdgcn_mfma_f32_16x16x32_bf16(ahi[3][1], L1, a3, 0, 0, 0);   \
    a0 = __builtin_amdgcn_mfma_f32_16x16x32_bf16(ahi[0][0], H0, a0, 0, 0, 0);   \
    a1 = __builtin_amdgcn_mfma_f32_16x16x32_bf16(ahi[1][0], H0, a1, 0, 0, 0);   \
    a2 = __builtin_amdgcn_mfma_f32_16x16x32_bf16(ahi[2][0], H0, a2, 0, 0, 0);   \
    a3 = __builtin_amdgcn_mfma_f32_16x16x32_bf16(ahi[3][0], H0, a3, 0, 0, 0);   \
    a0 = __builtin_amdgcn_mfma_f32_16x16x32_bf16(ahi[0][1], H1, a0, 0, 0, 0);   \
    a1 = __builtin_amdgcn_mfma_f32_16x16x32_bf16(ahi[1][1], H1, a1, 0, 0, 0);   \
    a2 = __builtin_amdgcn_mfma_f32_16x16x32_bf16(ahi[2][1], H1, a2, 0, 0, 0);   \
    a3 = __builtin_amdgcn_mfma_f32_16x16x32_bf16(ahi[3][1], H1, a3, 0, 0, 0);

#define SELECT_BLOCK(KT)                                                        \
    {                                                                           \
      unsigned invb = (unsigned)(nt16 - 1 - (KT) * 16 - n);                     \
      _Pragma("unroll") for (int r = 0; r < 4; r++) {                           \
        float x0 = __builtin_amdgcn_fmed3f(a0[r], 1.0f, hiclamp);               \
        unsigned kb0 = (__float_as_uint(x0) << 10) + invb;                      \
        run2[0][r] = max(run2[0][r], min(run1[0][r], kb0));                     \
        run1[0][r] = max(run1[0][r], kb0);                                      \
        float x1 = __builtin_amdgcn_fmed3f(a1[r], 1.0f, hiclamp);               \
        unsigned kb1 = (__float_as_uint(x1) << 10) + invb;                      \
        run2[1][r] = max(run2[1][r], min(run1[1][r], kb1));                     \
        run1[1][r] = max(run1[1][r], kb1);                                      \
        float x2 = __builtin_amdgcn_fmed3f(a2[r], 1.0f, hiclamp);               \
        unsigned kb2 = (__float_as_uint(x2) << 10) + invb;                      \
        run2[2][r] = max(run2[2][r], min(run1[2][r], kb2));                     \
        run1[2][r] = max(run1[2][r], kb2);                                      \
        float x3 = __builtin_amdgcn_fmed3f(a3[r], 1.0f, hiclamp);               \
        unsigned kb3 = (__float_as_uint(x3) << 10) + invb;                      \
        run2[3][r] = max(run2[3][r], min(run1[3][r], kb3));                     \
        run1[3][r] = max(run1[3][r], kb3);                                      \
      }                                                                         \
    }

#pragma unroll 1
  for (int kt = 0; kt < ntiles; kt += 2) {
    {
      MFMA_BLOCK(h0a, h1a, l0a, l1a)
      int off = (kt + 2) * 1024;
      h0a = *(const short8*)(bh + off);
      h1a = *(const short8*)(bh + off + 32);
      l0a = *(const short8*)(bl + off);
      l1a = *(const short8*)(bl + off + 32);
      SELECT_BLOCK(kt)
    }
    {
      MFMA_BLOCK(h0b, h1b, l0b, l1b)
      int off = (kt + 3) * 1024;
      h0b = *(const short8*)(bh + off);
      h1b = *(const short8*)(bh + off + 32);
      l0b = *(const short8*)(bl + off);
      l1b = *(const short8*)(bl + off + 32);
      SELECT_BLOCK(kt + 1)
    }
  }
#undef MFMA_BLOCK
#undef SELECT_BLOCK

  // butterfly top-2 merge across the 16 n-lanes
#pragma unroll
  for (int off = 1; off <= 8; off <<= 1) {
#pragma unroll
    for (int s = 0; s < 4; s++)
#pragma unroll
      for (int r = 0; r < 4; r++) {
        unsigned o1 = (unsigned)__shfl_xor((int)run1[s][r], off, 64);
        unsigned o2 = (unsigned)__shfl_xor((int)run2[s][r], off, 64);
        run2[s][r] = max(min(run1[s][r], o1), max(run2[s][r], o2));
        run1[s][r] = max(run1[s][r], o1);
      }
  }

  if (n == 0) {
#pragma unroll
    for (int s = 0; s < 4; s++)
#pragma unroll
      for (int r = 0; r < 4; r++) {
        int q = qw + s * 16 + g * 4 + r;
        pk1[split * N_TOK + q] = run1[s][r];
        pk2[split * N_TOK + q] = run2[s][r];
      }
  }
}

// ---- merge splits + in-kernel fp64 rescore of 12 candidates for flagged ----
// danger (possible hidden 3rd-in-split near max) -> rare full-rescan list.
__global__ __launch_bounds__(256) void k_merge_fix(const unsigned* __restrict__ pk1,
                                                   const unsigned* __restrict__ pk2,
                                                   const float* __restrict__ fn,
                                                   const float* __restrict__ emb,
                                                   int* __restrict__ idxw,
                                                   int* __restrict__ cnts,
                                                   int* __restrict__ full,
                                                   unsigned long long* __restrict__ fullkey) {
  __shared__ int nfl;
  __shared__ int fl[256][13];
  int t = threadIdx.x;
  if (t == 0) nfl = 0;
  __syncthreads();
  int q = blockIdx.x * 256 + t;
  unsigned k1v[SPLITS], k2v[SPLITS];
  unsigned b1 = 0u, b2 = 0u;
  int s1 = 0;
#pragma unroll
  for (int s = 0; s < SPLITS; s++) {
    unsigned k1 = pk1[s * N_TOK + q];
    unsigned k2 = pk2[s * N_TOK + q];
    k1v[s] = k1;
    k2v[s] = k2;
    b2 = max(b2, min(b1, k1));
    b2 = max(b2, k2);
    if (k1 > b1) { b1 = k1; s1 = s; }
  }
  int nt16s = (s1 < 2) ? 704 : 672;
  int ts16 = (s1 < 3) ? 704 * s1 : 672 * s1 + 64;
  idxw[q] = ts16 + nt16s - 1 - (int)(b1 & 1023u);
  fullkey[q] = 0ull;
  bool danger = false;
#pragma unroll
  for (int s = 0; s < SPLITS; s++) danger |= (k2v[s] + DGRKEY > b1);
  if (danger) {
    int p = atomicAdd(&cnts[0], 1);
    full[p] = q;
  } else if (b1 - b2 < THRKEY) {
    int p = atomicAdd(&nfl, 1);
    fl[p][0] = q;
#pragma unroll
    for (int s = 0; s < SPLITS; s++) {
      int nt = (s < 2) ? 704 : 672;
      int tss = (s < 3) ? 704 * s : 672 * s + 64;
      fl[p][1 + s] = tss + nt - 1 - (int)(k1v[s] & 1023u);
      fl[p][7 + s] = tss + nt - 1 - (int)(k2v[s] & 1023u);
    }
  }
  __syncthreads();
  int m = nfl;
  int wave = t >> 6, lane = t & 63;
  int c = lane >> 2, dg = lane & 3;
  for (int i = wave; i < m; i += 4) {
    int fq = fl[i][0];
    int code = (c < 12) ? fl[i][1 + c] : fl[i][1];
    const float* er = emb + code * 64 + dg * 16;
    const float* fr = fn + fq * 64 + dg * 16;
    double d = 0.0;
#pragma unroll
    for (int k = 0; k < 16; k++) d += (double)er[k] * (double)fr[k];
    d += __shfl_xor(d, 1, 64);  // same summation tree as k_fix_full
    d += __shfl_xor(d, 2, 64);
    unsigned long long key =
        ((unsigned long long)__double_as_longlong(d + 2.0) & ~0xFFFULL) |
        (unsigned long long)(4095 - code);
    if (c >= 12) key = 0ull;
#pragma unroll
    for (int off = 4; off <= 32; off <<= 1) {
      unsigned long long o = __shfl_xor(key, off, 64);
      key = key > o ? key : o;
    }
    if (lane == 0) idxw[fq] = 4095 - (int)(key & 0xFFFULL);
  }
}

// ---------------- exact fp64 full rescan (rare danger queries) --------------
__global__ __launch_bounds__(256) void k_fix_full(const int* __restrict__ cnts,
                                                  const int* __restrict__ full,
                                                  const float* __restrict__ fn,
                                                  const float* __restrict__ emb,
                                                  unsigned long long* __restrict__ fullkey) {
  __shared__ float sfn[64];
  __shared__ unsigned long long red[256];
  int t = threadIdx.x;
  int total = cnts[0] * 16;
  for (int w = blockIdx.x; w < total; w += gridDim.x) {
    int q = full[w >> 4];
    int c = (w & 15) * 256 + t;
    __syncthreads();
    if (t < 64) sfn[t] = fn[q * 64 + t];
    __syncthreads();
    const float* er = emb + c * 64;
    double s0 = 0, s1 = 0, s2 = 0, s3 = 0;
    for (int k = 0; k < 16; k++) {
      s0 += (double)er[k] * (double)sfn[k];
      s1 += (double)er[k + 16] * (double)sfn[k + 16];
      s2 += (double)er[k + 32] * (double)sfn[k + 32];
      s3 += (double)er[k + 48] * (double)sfn[k + 48];
    }
    double d = (s0 + s1) + (s2 + s3);
    unsigned long long key =
        ((unsigned long long)__double_as_longlong(d + 2.0) & ~0xFFFULL) |
        (unsigned long long)(4095 - c);
    red[t] = key;
    __syncthreads();
    for (int s = 128; s > 0; s >>= 1) {
      if (t < s) red[t] = red[t] > red[t + s] ? red[t] : red[t + s];
      __syncthreads();
    }
    if (t == 0) atomicMax(&fullkey[q], red[0]);
  }
}

// ---------------- write z_q, z_q_st, indices + scatter stats ----------------
__global__ __launch_bounds__(256) void k_write_scatter(const int* __restrict__ idxw,
                                                       const unsigned long long* __restrict__ fullkey,
                                                       const float* __restrict__ z_e,
                                                       const float* __restrict__ emb,
                                                       const float* __restrict__ fn,
                                                       float* __restrict__ out,
                                                       float* __restrict__ esum,
                                                       float* __restrict__ usage) {
  int t = threadIdx.x;
  int nn = blockIdx.x * 4 + (t >> 6);
  int lane = t & 63;
  unsigned long long fk = fullkey[nn];
  int bi = fk ? (4095 - (int)(fk & 0xFFFULL)) : idxw[nn];
  float v = emb[bi * 64 + lane];
  float ze = z_e[nn * 64 + lane];
  out[OFF_ZQST + nn * 64 + lane] = ze + (v - ze);
  out[OFF_ZQ + nn * 64 + lane] = v;
  atomicAdd(&esum[bi * 64 + lane], fn[nn * 64 + lane]);
  if (lane == 0) {
    out[OFF_IDX + nn] = (float)bi;
    atomicAdd(&usage[bi], 1.0f);
  }
}

// ---- stats partials (16 blocks): usage.sum()==32768 exactly ----
__global__ __launch_bounds__(256) void k_stats(const float* __restrict__ usage,
                                               const float* __restrict__ ema_cs,
                                               float* __restrict__ scal) {
  __shared__ float rE[4], rD[4], rC[4];
  int t = threadIdx.x;
  int i = blockIdx.x * 256 + t;  // 0..4095
  float u = usage[i];
  float p = u * (1.0f / 32768.0f);
  float ent = (p > 0.f) ? p * logf(p) : 0.f;
  float dead = (u == 0.f) ? 1.f : 0.f;
  float cs = 0.99f * ema_cs[i] + 0.01f * u;
  ent = wave_sum(ent);
  dead = wave_sum(dead);
  cs = wave_sum(cs);
  int w = t >> 6, lane = t & 63;
  if (lane == 0) { rE[w] = ent; rD[w] = dead; rC[w] = cs; }
  __syncthreads();
  if (t == 0) {
    atomicAdd(&scal[0], rE[0] + rE[1] + rE[2] + rE[3]);
    atomicAdd(&scal[1], rD[0] + rD[1] + rD[2] + rD[3]);
    atomicAdd(&scal[2], rC[0] + rC[1] + rC[2] + rC[3]);
  }
}

// ---------------- new_cs, new_ema_emb, new_embedding, stats assembly --------
__global__ __launch_bounds__(256) void k_final(const float* __restrict__ usage,
                                               const float* __restrict__ ema_cs,
                                               const float* __restrict__ ema_emb,
                                               const float* __restrict__ esum,
                                               const float* __restrict__ fn,
                                               const int* __restrict__ ridx,
                                               const float* __restrict__ scal,
                                               float* __restrict__ out) {
  int t = threadIdx.x;
  int k = blockIdx.x * 4 + (t >> 6);
  int lane = t & 63;
  if (blockIdx.x == 0 && t == 0) {
    out[OFF_STATS + 0] = expf(-scal[0]);
    out[OFF_STATS + 1] = scal[1] * (1.0f / 4096.0f);
  }
  float u = usage[k];
  float ncs = 0.99f * ema_cs[k] + 0.01f * u;
  if (lane == 0) out[OFF_NEWCS + k] = ncs;
  float nee = 0.99f * ema_emb[k * 64 + lane] + 0.01f * esum[k * 64 + lane];
  out[OFF_NEWEMA + k * 64 + lane] = nee;

  float n = scal[2];
  float smoothed = (ncs + 1e-5f) / (n + 4096.0f * 1e-5f);
  float ne = nee / fmaxf(smoothed, 1e-5f);
  float ss = wave_sum(ne * ne);
  ne = ne / fmaxf(sqrtf(ss), 1e-8f);

  float res;
  if (u <= 0.f) {
    int rsrc = ridx[k];
    float v = fn[rsrc * 64 + lane];
    float s2 = wave_sum(v * v);
    res = v / fmaxf(sqrtf(s2), 1e-8f);
  } else {
    res = ne;
  }
  out[OFF_NEWEMB + k * 64 + lane] = res;
}

extern "C" void kernel_launch(void* const* d_in, const int* in_sizes, int n_in,
                              void* d_out, int out_size, void* d_ws, size_t ws_size,
                              hipStream_t stream) {
  const float* z_e = (const float*)d_in[0];
  const float* emb = (const float*)d_in[1];
  const float* ema_cs = (const float*)d_in[2];
  const float* ema_emb = (const float*)d_in[3];
  float* out = (float*)d_out;
  char* ws = (char*)d_ws;

  float* fn = (float*)(ws + WS_FN);
  float* esum = (float*)(ws + WS_ESUM);
  float* usage = (float*)(ws + WS_USAGE);
  int* cnts = (int*)(ws + WS_CNTS);
  float* scal = (float*)(ws + WS_CNTS + 16);
  unsigned long long* fullkey = (unsigned long long*)(ws + WS_FULLKEY);
  unsigned short* ehi = (unsigned short*)(ws + WS_EHI);
  unsigned short* elo = (unsigned short*)(ws + WS_ELO);
  unsigned* pk1 = (unsigned*)(ws + WS_PK1);
  unsigned* pk2 = (unsigned*)(ws + WS_PK2);
  int* idxw = (int*)(ws + WS_IDXW);
  int* ridx = (int*)(ws + WS_RIDX);
  int* full = (int*)(ws + WS_FULL);

  k_prep<<<10265, 256, 0, stream>>>(z_e, emb, fn, ehi, elo, ridx, (int*)(ws + WS_ESUM));
  k_dots<<<dim3(128, SPLITS), 256, 0, stream>>>(fn, ehi, elo, pk1, pk2);
  k_merge_fix<<<128, 256, 0, stream>>>(pk1, pk2, fn, emb, idxw, cnts, full, fullkey);
  k_fix_full<<<512, 256, 0, stream>>>(cnts, full, fn, emb, fullkey);
  k_write_scatter<<<8192, 256, 0, stream>>>(idxw, fullkey, z_e, emb, fn, out, esum, usage);
  k_stats<<<16, 256, 0, stream>>>(usage, ema_cs, scal);
  k_final<<<1024, 256, 0, stream>>>(usage, ema_cs, ema_emb, esum, fn, ridx, scal, out);
}